// Round 7
// baseline (324.268 us; speedup 1.0000x reference)
//
#include <hip/hip_runtime.h>
#include <hip/hip_bf16.h>

typedef __attribute__((ext_vector_type(4))) float floatx4;
typedef __attribute__((ext_vector_type(8))) short shortx8;

struct bf4 { __hip_bfloat16 h[4]; };
union U8 { shortx8 v; __hip_bfloat16 h[8]; };
union U4 { unsigned long long v; __hip_bfloat16 h[4]; };

__device__ __forceinline__ void async_copy16(const __hip_bfloat16* g, __hip_bfloat16* l) {
  __builtin_amdgcn_global_load_lds((__attribute__((address_space(1))) void*)g,
                                   (__attribute__((address_space(3))) void*)l,
                                   16, 0, 0);
}

// ---------------------------------------------------------------------------
// One-launch fp32 -> bf16 cast over 5 ranges (x, Wqkv, Wo, W1, W2).
// ---------------------------------------------------------------------------
__global__ __launch_bounds__(256) void cast_all_kernel(
    const float* __restrict__ s0, __hip_bfloat16* __restrict__ d0, int nb0,
    const float* __restrict__ s1, __hip_bfloat16* __restrict__ d1, int nb1,
    const float* __restrict__ s2, __hip_bfloat16* __restrict__ d2, int nb2,
    const float* __restrict__ s3, __hip_bfloat16* __restrict__ d3, int nb3,
    const float* __restrict__ s4, __hip_bfloat16* __restrict__ d4) {
  int b = blockIdx.x;
  const float* src; __hip_bfloat16* dst;
  if (b < nb0) { src = s0; dst = d0; }
  else { b -= nb0;
    if (b < nb1) { src = s1; dst = d1; }
    else { b -= nb1;
      if (b < nb2) { src = s2; dst = d2; }
      else { b -= nb2;
        if (b < nb3) { src = s3; dst = d3; }
        else { b -= nb3; src = s4; dst = d4; }
      }
    }
  }
  const int i = b * 256 + threadIdx.x;
  const float4 v = ((const float4*)src)[i];
  bf4 o4;
  o4.h[0] = __float2bfloat16(v.x);
  o4.h[1] = __float2bfloat16(v.y);
  o4.h[2] = __float2bfloat16(v.z);
  o4.h[3] = __float2bfloat16(v.w);
  *(bf4*)(dst + (size_t)i * 4) = o4;
}

// ===========================================================================
// Round 12: 256x256 GEMM, 16 waves (1024 thr), 64x64 output per wave.
// Mechanism: the 8-wave engine needs ~240 regs/wave (128 acc) -> 2 waves/SIMD
// and ~70% lockstep stall (MfmaUtil 27%). 64x64/wave -> acc 64 regs, total
// <=128 -> 4 waves/SIMD (launch_bounds(1024,4)): waves at offset points in
// the phase hide each other's lgkm/vmcnt/barrier-skew latency.
// LDS ring of 4 k-half slots per operand ([256 rows][32 k] bf16 = 16 KB each,
// 128 KiB total). Phase u (slot u&3, one phase per k-half, 16 indep MFMA):
//   reads(u): 4 A + 4 B ds_read_b128 (slot u validated last phase)
//   stage(u+3): 1 A + 1 B global_load_lds (1024 thr x 16B = whole slot)
//   vmcnt(4)  // outstanding u+1..u+3 = 6; drains u+1 -> valid next phase
//   BAR       // publish
//   lgkm0; sched_barrier; setprio(1); 16 MFMA (K=32, all indep); setprio(0)
//   BAR       // reads(u) drained above -> restage of (u-1)&3 next phase safe
// Tail (last 3 phases): vmcnt 2/0/none. Prologue: stage 0,1,2; vmcnt(4); BAR.
// LDS swizzle unchanged (verified conflicts=0): read phys chunk =
// fq^((fr>>1)&3); staging thread t covers phys chunk t&3 of row t>>2 ->
// source k-chunk (t&3)^((t>>3)&3) (involution).
// Requires NH = K/32 multiple of 4, >= 8 (call sites: NH = 32 or 8).
// ===========================================================================
#define G5_VM(n)   asm volatile("s_waitcnt vmcnt(" #n ")" ::: "memory")
#define G5_BAR()   asm volatile("s_barrier" ::: "memory")
#define G5_LGKM0() asm volatile("s_waitcnt lgkmcnt(0)" ::: "memory")
#define G5_SB()    __builtin_amdgcn_sched_barrier(0)

#define G5_STAGE(slot, koff)                                                   \
  async_copy16(Ag + (koff), &As[slot][tid * 8]);                               \
  async_copy16(Bg + (koff), &Bs[slot][tid * 8]);

#define G5_PHASE(slot, SOFF, DOSTG, VMW)                                       \
  {                                                                            \
    shortx8 fa[4], fb[4];                                                      \
    _Pragma("unroll")                                                          \
    for (int i_ = 0; i_ < 4; ++i_)                                             \
      fa[i_] = *(const shortx8*)&As[slot][ard + i_ * 512];                     \
    _Pragma("unroll")                                                          \
    for (int i_ = 0; i_ < 4; ++i_)                                             \
      fb[i_] = *(const shortx8*)&Bs[slot][brd + i_ * 512];                     \
    if (DOSTG) { G5_STAGE((((slot) + 3) & 3), SOFF) }                          \
    VMW;                                                                       \
    G5_BAR();                                                                  \
    G5_LGKM0(); G5_SB();                                                       \
    __builtin_amdgcn_s_setprio(1);                                             \
    _Pragma("unroll")                                                          \
    for (int mi_ = 0; mi_ < 4; ++mi_)                                          \
      _Pragma("unroll")                                                        \
      for (int ni_ = 0; ni_ < 4; ++ni_)                                        \
        acc[mi_][ni_] = __builtin_amdgcn_mfma_f32_16x16x32_bf16(               \
            fa[mi_], fb[ni_], acc[mi_][ni_], 0, 0, 0);                         \
    __builtin_amdgcn_s_setprio(0);                                             \
    G5_SB();                                                                   \
    G5_BAR();                                                                  \
  }

#define G5_KLOOP()                                                             \
  G5_STAGE(0, 0) G5_STAGE(1, 32) G5_STAGE(2, 64)                               \
  G5_VM(4); G5_BAR();                                                          \
  const int NITER = (NH - 4) >> 2;                                             \
  _Pragma("clang loop unroll(disable)")                                        \
  for (int it = 0; it < NITER; ++it) {                                         \
    G5_PHASE(0, 96,  true, G5_VM(4))                                           \
    G5_PHASE(1, 128, true, G5_VM(4))                                           \
    G5_PHASE(2, 160, true, G5_VM(4))                                           \
    G5_PHASE(3, 192, true, G5_VM(4))                                           \
    Ag += 128; Bg += 128;                                                      \
  }                                                                            \
  G5_PHASE(0, 96, true, G5_VM(4))                                              \
  G5_PHASE(1, 0, false, G5_VM(2))                                              \
  G5_PHASE(2, 0, false, G5_VM(0))                                              \
  G5_PHASE(3, 0, false, (void)0)

// C[M,N] = A[M,K] * B[N,K]^T, bf16 in, fp32 acc, 256x256 tile, 1024 threads.
// EPI: 0 = +bias -> bf16; 1 = +bias, gelu -> bf16
template<int EPI>
__global__ __launch_bounds__(1024, 4) void gemm256(
    const __hip_bfloat16* __restrict__ A,   // [M,K]
    const __hip_bfloat16* __restrict__ B,   // [N,K]
    const float* __restrict__ bias,         // [N]
    __hip_bfloat16* __restrict__ outb,
    int M, int N, int K, int NT)
{
  __shared__ __align__(16) __hip_bfloat16 As[4][256 * 32];
  __shared__ __align__(16) __hip_bfloat16 Bs[4][256 * 32];
  const int tid  = threadIdx.x;
  const int lane = tid & 63;
  const int wave = tid >> 6;        // 0..15
  const int wr = wave >> 2;         // 0..3 (64-row band)
  const int wc = wave & 3;          // 0..3 (64-col band)
  const int fr = lane & 15;
  const int fq = lane >> 4;         // 0..3

  // bijective XCD swizzle (nwg % 8 == 0 for all call sites)
  const int nwg = gridDim.x;
  const int cpx = nwg >> 3;
  const int swz = (blockIdx.x & 7) * cpx + (blockIdx.x >> 3);
  const int mt = swz / NT, nt = swz % NT;
  const long bm = (long)mt * 256, bn = (long)nt * 256;

  // staging: thread t covers phys 16B-chunk (t&3) of row (t>>2) of a slot
  const int srow = tid >> 2;                       // 0..255
  const int sch  = (tid & 3) ^ ((tid >> 3) & 3);   // source k-chunk (involution)
  const __hip_bfloat16* Ag = A + (bm + srow) * (size_t)K + sch * 8;
  const __hip_bfloat16* Bg = B + (bn + srow) * (size_t)K + sch * 8;

  // ds_read bases (elements), swizzled chunk = fq ^ ((fr>>1)&3)
  const int swc = (fq ^ ((fr >> 1) & 3)) << 3;
  const int ard = (wr * 64 + fr) * 32 + swc;
  const int brd = (wc * 64 + fr) * 32 + swc;

  const floatx4 zero = {0.f, 0.f, 0.f, 0.f};
  floatx4 acc[4][4];
#pragma unroll
  for (int mi = 0; mi < 4; ++mi)
#pragma unroll
    for (int ni = 0; ni < 4; ++ni) acc[mi][ni] = zero;

  const int NH = K >> 5;            // k-halves of 32 (mult of 4, >= 8)
  G5_KLOOP()

  // epilogue: C/D layout col = lane&15, row = (lane>>4)*4 + reg
#pragma unroll
  for (int mi = 0; mi < 4; ++mi) {
#pragma unroll
    for (int ni = 0; ni < 4; ++ni) {
      const long col = bn + wc * 64 + ni * 16 + fr;
      const float bv = bias[col];
#pragma unroll
      for (int r = 0; r < 4; ++r) {
        const long row = bm + wr * 64 + mi * 16 + fq * 4 + r;
        float v = acc[mi][ni][r] + bv;
        if (EPI == 1) {
          const float u = v + 0.044715f * v * v * v;
          v = v / (1.0f + __expf(-1.5957691216057308f * u));
        }
        outb[(size_t)row * N + col] = __float2bfloat16(v);
      }
    }
  }
}

// ---------------------------------------------------------------------------
// 256x256 split-K GEMM (same engine) -> bf16 partials [SPLITS, M, N].
// attn-out: Klen=256 (NH=8); FFN2: Klen=1024 (NH=32).
// ---------------------------------------------------------------------------
__global__ __launch_bounds__(1024, 4) void gemm256_splitk(
    const __hip_bfloat16* __restrict__ A,   // [M,K]
    const __hip_bfloat16* __restrict__ B,   // [N,K]
    __hip_bfloat16* __restrict__ part,      // [SPLITS, M, N]
    int M, int N, int K, int Klen, int NT, int TPS)
{
  __shared__ __align__(16) __hip_bfloat16 As[4][256 * 32];
  __shared__ __align__(16) __hip_bfloat16 Bs[4][256 * 32];
  const int tid  = threadIdx.x;
  const int lane = tid & 63;
  const int wave = tid >> 6;
  const int wr = wave >> 2;
  const int wc = wave & 3;
  const int fr = lane & 15;
  const int fq = lane >> 4;

  const int nwg = gridDim.x;
  const int cpx = nwg >> 3;
  const int swz = (blockIdx.x & 7) * cpx + (blockIdx.x >> 3);
  const int zt = swz / TPS;
  const int tile = swz % TPS;
  const int mt = tile / NT, nt = tile % NT;
  const long bm = (long)mt * 256, bn = (long)nt * 256;
  const int kstart = zt * Klen;

  const int srow = tid >> 2;
  const int sch  = (tid & 3) ^ ((tid >> 3) & 3);
  const __hip_bfloat16* Ag = A + (bm + srow) * (size_t)K + kstart + sch * 8;
  const __hip_bfloat16* Bg = B + (bn + srow) * (size_t)K + kstart + sch * 8;

  const int swc = (fq ^ ((fr >> 1) & 3)) << 3;
  const int ard = (wr * 64 + fr) * 32 + swc;
  const int brd = (wc * 64 + fr) * 32 + swc;

  const floatx4 zero = {0.f, 0.f, 0.f, 0.f};
  floatx4 acc[4][4];
#pragma unroll
  for (int mi = 0; mi < 4; ++mi)
#pragma unroll
    for (int ni = 0; ni < 4; ++ni) acc[mi][ni] = zero;

  const int NH = Klen >> 5;
  G5_KLOOP()

  __hip_bfloat16* outp = part + (size_t)zt * M * N;
#pragma unroll
  for (int mi = 0; mi < 4; ++mi) {
#pragma unroll
    for (int ni = 0; ni < 4; ++ni) {
      const long col = bn + wc * 64 + ni * 16 + fr;
#pragma unroll
      for (int r = 0; r < 4; ++r) {
        const long row = bm + wr * 64 + mi * 16 + fq * 4 + r;
        outp[(size_t)row * N + col] = __float2bfloat16(acc[mi][ni][r]);
      }
    }
  }
}

// ---------------------------------------------------------------------------
// V transpose: qkv v-part [token, h*64+d] -> vt[(bh*64+d)*1024 + token]
// ---------------------------------------------------------------------------
__global__ __launch_bounds__(256) void transpose_v_kernel(
    const __hip_bfloat16* __restrict__ qkv, __hip_bfloat16* __restrict__ vt)
{
  const int bh = blockIdx.y;
  const int tt = blockIdx.x;
  const int b = bh >> 4, h = bh & 15;
  __shared__ __hip_bfloat16 tile[64][65];
  const int tid = threadIdx.x;
  const int r = tid >> 2;
  const int c = (tid & 3) << 4;
  const __hip_bfloat16* src = qkv + (size_t)(b * 1024 + tt * 64 + r) * 3072 + 2048 + h * 64 + c;
  U8 u0, u1;
  u0.v = *(const shortx8*)src;
  u1.v = *(const shortx8*)(src + 8);
#pragma unroll
  for (int j = 0; j < 8; ++j) { tile[r][c + j] = u0.h[j]; tile[r][c + 8 + j] = u1.h[j]; }
  __syncthreads();
  U8 w0, w1;
#pragma unroll
  for (int j = 0; j < 8; ++j) { w0.h[j] = tile[c + j][r]; w1.h[j] = tile[c + 8 + j][r]; }
  __hip_bfloat16* dst = vt + ((size_t)bh * 64 + r) * 1024 + tt * 64 + c;
  *(shortx8*)dst       = w0.v;
  *(shortx8*)(dst + 8) = w1.v;
}

// ---------------------------------------------------------------------------
// Banded-causal flash attention. One wave per (b,h,q-tile of 16).
// ---------------------------------------------------------------------------
__global__ __launch_bounds__(256) void attn_kernel(
    const __hip_bfloat16* __restrict__ qkv,
    const __hip_bfloat16* __restrict__ vt,
    __hip_bfloat16* __restrict__ ctx)
{
  const int wave = threadIdx.x >> 6;
  const int lane = threadIdx.x & 63;
  const int gw = blockIdx.x * 4 + wave;
  const int qt = gw & 63;
  const int bh = gw >> 6;
  const int b = bh >> 4, h = bh & 15;
  const int fr = lane & 15, fq = lane >> 4;
  const int q0 = qt << 4;

  __shared__ __align__(16) __hip_bfloat16 Plds[4][16 * 32];
  __hip_bfloat16* Pw = Plds[wave];

  const __hip_bfloat16* qrow = qkv + (size_t)(b * 1024 + q0 + fr) * 3072 + h * 64;
  const shortx8 aq0 = *(const shortx8*)(qrow + fq * 8);
  const shortx8 aq1 = *(const shortx8*)(qrow + 32 + fq * 8);

  const float SC = 0.125f * 1.44269504088896f;
  float m_r[4] = {-1e30f, -1e30f, -1e30f, -1e30f};
  float l_r[4] = {0.f, 0.f, 0.f, 0.f};
  const floatx4 zero = {0.f, 0.f, 0.f, 0.f};
  floatx4 o[4];
#pragma unroll
  for (int nd = 0; nd < 4; ++nd) o[nd] = zero;

  const int kt0 = (q0 >= 255) ? ((q0 - 255) >> 5) : 0;
  const int kt1 = (q0 + 15) >> 5;
  for (int kt = kt0; kt <= kt1; ++kt) {
    const int kbase = kt << 5;
    const __hip_bfloat16* krow0 = qkv + (size_t)(b * 1024 + kbase + fr) * 3072 + 1024 + h * 64;
    const __hip_bfloat16* krow1 = krow0 + 16 * 3072;
    const shortx8 bk00 = *(const shortx8*)(krow0 + fq * 8);
    const shortx8 bk01 = *(const shortx8*)(krow0 + 32 + fq * 8);
    const shortx8 bk10 = *(const shortx8*)(krow1 + fq * 8);
    const shortx8 bk11 = *(const shortx8*)(krow1 + 32 + fq * 8);
    floatx4 s0 = zero, s1 = zero;
    s0 = __builtin_amdgcn_mfma_f32_16x16x32_bf16(aq0, bk00, s0, 0, 0, 0);
    s0 = __builtin_amdgcn_mfma_f32_16x16x32_bf16(aq1, bk01, s0, 0, 0, 0);
    s1 = __builtin_amdgcn_mfma_f32_16x16x32_bf16(aq0, bk10, s1, 0, 0, 0);
    s1 = __builtin_amdgcn_mfma_f32_16x16x32_bf16(aq1, bk11, s1, 0, 0, 0);
#pragma unroll
    for (int r = 0; r < 4; ++r) { s0[r] *= SC; s1[r] *= SC; }
    if (kbase + 31 > q0 || kbase < q0 - 240) {
#pragma unroll
      for (int r = 0; r < 4; ++r) {
        const int tq = q0 + fq * 4 + r;
        const int j0 = kbase + fr;
        const int j1 = j0 + 16;
        if (j0 > tq || j0 < tq - 255) s0[r] = -3e38f;
        if (j1 > tq || j1 < tq - 255) s1[r] = -3e38f;
      }
    }
#pragma unroll
    for (int r = 0; r < 4; ++r) {
      float vmax = fmaxf(s0[r], s1[r]);
      vmax = fmaxf(vmax, __shfl_xor(vmax, 1));
      vmax = fmaxf(vmax, __shfl_xor(vmax, 2));
      vmax = fmaxf(vmax, __shfl_xor(vmax, 4));
      vmax = fmaxf(vmax, __shfl_xor(vmax, 8));
      const float mnew = fmaxf(m_r[r], vmax);
      const float alpha = exp2f(m_r[r] - mnew);
      const float p0 = exp2f(s0[r] - mnew);
      const float p1 = exp2f(s1[r] - mnew);
      m_r[r] = mnew;
      float ps = p0 + p1;
      ps += __shfl_xor(ps, 1);
      ps += __shfl_xor(ps, 2);
      ps += __shfl_xor(ps, 4);
      ps += __shfl_xor(ps, 8);
      l_r[r] = l_r[r] * alpha + ps;
      o[0][r] *= alpha; o[1][r] *= alpha; o[2][r] *= alpha; o[3][r] *= alpha;
      Pw[(fq * 4 + r) * 32 + fr]      = __float2bfloat16(p0);
      Pw[(fq * 4 + r) * 32 + 16 + fr] = __float2bfloat16(p1);
    }
    asm volatile("s_waitcnt lgkmcnt(0)" ::: "memory");
    const shortx8 ap = *(const shortx8*)&Pw[fr * 32 + fq * 8];
#pragma unroll
    for (int nd = 0; nd < 4; ++nd) {
      const shortx8 bv = *(const shortx8*)&vt[((size_t)bh * 64 + nd * 16 + fr) * 1024 + kbase + fq * 8];
      o[nd] = __builtin_amdgcn_mfma_f32_16x16x32_bf16(ap, bv, o[nd], 0, 0, 0);
    }
    asm volatile("s_waitcnt lgkmcnt(0)" ::: "memory");
  }
#pragma unroll
  for (int nd = 0; nd < 4; ++nd)
#pragma unroll
    for (int r = 0; r < 4; ++r)
      ctx[(size_t)(b * 1024 + q0 + fq * 4 + r) * 1024 + h * 64 + nd * 16 + fr] =
          __float2bfloat16(o[nd][r] / l_r[r]);
}

// ---------------------------------------------------------------------------
// Fused split-K reduce (bf16 partials) + bias + residual + LayerNorm.
// ---------------------------------------------------------------------------
template<int S, int WB>
__global__ __launch_bounds__(256) void ln_sum_kernel(
    const __hip_bfloat16* __restrict__ part,  // [S, 4096, 1024] bf16
    const float* __restrict__ resid,          // [4096, 1024]
    const float* __restrict__ bias,           // [1024]
    const float* __restrict__ g, const float* __restrict__ be,
    float* __restrict__ outf, __hip_bfloat16* __restrict__ outb)
{
  const int row = blockIdx.x;
  const int tid = threadIdx.x;
  const size_t base = (size_t)row * 1024;
  float4 v = ((const float4*)(resid + base))[tid];
  const float4 bv = ((const float4*)bias)[tid];
  v.x += bv.x; v.y += bv.y; v.z += bv.z; v.w += bv.w;
#pragma unroll
  for (int s = 0; s < S; ++s) {
    U4 p;
    p.v = *(const unsigned long long*)&part[(size_t)s * 4096 * 1024 + base + tid * 4];
    v.x += __bfloat162float(p.h[0]);
    v.y += __bfloat162float(p.h[1]);
    v.z += __bfloat162float(p.h[2]);
    v.w += __bfloat162float(p.h[3]);
  }
  float sm = v.x + v.y + v.z + v.w;
  float ss = v.x * v.x + v.y * v.y + v.z * v.z + v.w * v.w;
#pragma unroll
  for (int off = 1; off < 64; off <<= 1) {
    sm += __shfl_xor(sm, off);
    ss += __shfl_xor(ss, off);
  }
  __shared__ float red[8];
  if ((tid & 63) == 0) { red[tid >> 6] = sm; red[4 + (tid >> 6)] = ss; }
  __syncthreads();
  sm = red[0] + red[1] + red[2] + red[3];
  ss = red[4] + red[5] + red[6] + red[7];
  const float mu = sm * (1.0f / 1024.0f);
  const float rs = rsqrtf(ss * (1.0f / 1024.0f) - mu * mu + 1e-5f);
  const float4 gg = ((const float4*)g)[tid];
  const float4 bb = ((const float4*)be)[tid];
  float4 y;
  y.x = (v.x - mu) * rs * gg.x + bb.x;
  y.y = (v.y - mu) * rs * gg.y + bb.y;
  y.z = (v.z - mu) * rs * gg.z + bb.z;
  y.w = (v.w - mu) * rs * gg.w + bb.w;
  ((float4*)(outf + base))[tid] = y;
  if (WB) {
    bf4 o4;
    o4.h[0] = __float2bfloat16(y.x);
    o4.h[1] = __float2bfloat16(y.y);
    o4.h[2] = __float2bfloat16(y.z);
    o4.h[3] = __float2bfloat16(y.w);
    *(bf4*)(outb + base + tid * 4) = o4;
  }
}

// ---------------------------------------------------------------------------
extern "C" void kernel_launch(void* const* d_in, const int* in_sizes, int n_in,
                              void* d_out, int out_size, void* d_ws, size_t ws_size,
                              hipStream_t stream) {
  const float* x    = (const float*)d_in[0];
  const float* Wqkv = (const float*)d_in[1];
  const float* bqkv = (const float*)d_in[2];
  const float* Wo   = (const float*)d_in[3];
  const float* bo   = (const float*)d_in[4];
  const float* W1   = (const float*)d_in[5];
  const float* b1   = (const float*)d_in[6];
  const float* W2   = (const float*)d_in[7];
  const float* b2   = (const float*)d_in[8];
  const float* g1   = (const float*)d_in[9];
  const float* be1  = (const float*)d_in[10];
  const float* g2   = (const float*)d_in[11];
  const float* be2  = (const float*)d_in[12];

  char* ws = (char*)d_ws;
  size_t off = 0;
  auto alloc = [&](size_t bytes) -> void* {
    void* p = ws + off;
    off += (bytes + 255) & ~(size_t)255;
    return p;
  };
  __hip_bfloat16* wqkvb = (__hip_bfloat16*)alloc(6291456);
  __hip_bfloat16* wob   = (__hip_bfloat16*)alloc(2097152);
  __hip_bfloat16* w1b   = (__hip_bfloat16*)alloc(8388608);
  __hip_bfloat16* w2b   = (__hip_bfloat16*)alloc(8388608);
  __hip_bfloat16* xb    = (__hip_bfloat16*)alloc(8388608);
  __hip_bfloat16* qkvb  = (__hip_bfloat16*)alloc(25165824);
  __hip_bfloat16* vtb   = (__hip_bfloat16*)alloc(8388608);
  __hip_bfloat16* ctxb  = (__hip_bfloat16*)alloc(8388608);
  __hip_bfloat16* part  = (__hip_bfloat16*)alloc(4u * 8388608);
  float*          x1f   = (float*)alloc(16777216);
  __hip_bfloat16* x1b   = (__hip_bfloat16*)alloc(8388608);
  __hip_bfloat16* hb    = (__hip_bfloat16*)alloc(33554432);
  (void)ws_size; (void)in_sizes; (void)n_in; (void)out_size;

  // 0. single-launch cast of x + all weights to bf16
  cast_all_kernel<<<16384, 256, 0, stream>>>(x, xb, 4096,
                                             Wqkv, wqkvb, 3072,
                                             Wo, wob, 1024,
                                             W1, w1b, 4096,
                                             W2, w2b);
  // 1. QKV projection (256x256, 16-wave, 192 wgs)
  gemm256<0><<<192, 1024, 0, stream>>>(xb, wqkvb, bqkv, qkvb, 4096, 3072, 1024, 12);
  // 2. attention
  transpose_v_kernel<<<dim3(16, 64), 256, 0, stream>>>(qkvb, vtb);
  attn_kernel<<<1024, 256, 0, stream>>>(qkvb, vtb, ctxb);
  // 3. output projection: split-K=4 (64 tiles x 4 = 256 wgs, NH=8)
  gemm256_splitk<<<256, 1024, 0, stream>>>(ctxb, wob, part, 4096, 1024, 1024, 256, 4, 64);
  ln_sum_kernel<4, 1><<<4096, 256, 0, stream>>>(part, x, bo, g1, be1, x1f, x1b);
  // 4. FFN (FFN1: 256 wgs = 1/CU)
  gemm256<1><<<256, 1024, 0, stream>>>(x1b, w1b, b1, hb, 4096, 4096, 1024, 16);
  // FFN2: split-K=4 (64 tiles x 4 splits = 256 wgs, NH=32)
  gemm256_splitk<<<256, 1024, 0, stream>>>(hb, w2b, part, 4096, 1024, 4096, 1024, 4, 64);
  ln_sum_kernel<4, 0><<<4096, 256, 0, stream>>>(part, x1f, b2, g2, be2, (float*)d_out, nullptr);
}

// Round 8
// 309.481 us; speedup vs baseline: 1.0478x; 1.0478x over previous
//
#include <hip/hip_runtime.h>
#include <hip/hip_bf16.h>

typedef __attribute__((ext_vector_type(4))) float floatx4;
typedef __attribute__((ext_vector_type(8))) short shortx8;

struct bf4 { __hip_bfloat16 h[4]; };
union U8 { shortx8 v; __hip_bfloat16 h[8]; };
union U4 { unsigned long long v; __hip_bfloat16 h[4]; };

__device__ __forceinline__ void async_copy16(const __hip_bfloat16* g, __hip_bfloat16* l) {
  __builtin_amdgcn_global_load_lds((__attribute__((address_space(1))) void*)g,
                                   (__attribute__((address_space(3))) void*)l,
                                   16, 0, 0);
}

// ---------------------------------------------------------------------------
// One-launch fp32 -> bf16 cast over 5 ranges (x, Wqkv, Wo, W1, W2).
// ---------------------------------------------------------------------------
__global__ __launch_bounds__(256) void cast_all_kernel(
    const float* __restrict__ s0, __hip_bfloat16* __restrict__ d0, int nb0,
    const float* __restrict__ s1, __hip_bfloat16* __restrict__ d1, int nb1,
    const float* __restrict__ s2, __hip_bfloat16* __restrict__ d2, int nb2,
    const float* __restrict__ s3, __hip_bfloat16* __restrict__ d3, int nb3,
    const float* __restrict__ s4, __hip_bfloat16* __restrict__ d4) {
  int b = blockIdx.x;
  const float* src; __hip_bfloat16* dst;
  if (b < nb0) { src = s0; dst = d0; }
  else { b -= nb0;
    if (b < nb1) { src = s1; dst = d1; }
    else { b -= nb1;
      if (b < nb2) { src = s2; dst = d2; }
      else { b -= nb2;
        if (b < nb3) { src = s3; dst = d3; }
        else { b -= nb3; src = s4; dst = d4; }
      }
    }
  }
  const int i = b * 256 + threadIdx.x;
  const float4 v = ((const float4*)src)[i];
  bf4 o4;
  o4.h[0] = __float2bfloat16(v.x);
  o4.h[1] = __float2bfloat16(v.y);
  o4.h[2] = __float2bfloat16(v.z);
  o4.h[3] = __float2bfloat16(v.w);
  *(bf4*)(dst + (size_t)i * 4) = o4;
}

// ===========================================================================
// Round 13: 256x256 GEMM, 16 waves, ONE barrier per phase, 5-slot LDS ring
// (160 KiB = full CU LDS). Mechanism: with 2 asm barriers/phase the LDS-read
// burst (~1536 cyc/phase, CU-shared pipe) and the MFMA burst (~1242 cyc)
// strictly serialize -> 3600 cyc/phase, MfmaUtil 28% (r2/r6 both). One
// barrier per phase puts MFMA(u-1) and reads(u)+stage(u) in the SAME window
// on DIFFERENT pipes -> they overlap across the 4 waves/SIMD.
// Phase u (slot = u%5, k-half of 32, 16 indep MFMA/wave):
//   reads(u): 4 A + 4 B ds_read_b128 from slot u%5
//   stage: khalf u+3 -> slot (u+3)%5 (2 global_load_lds); vmcnt(4)
//   BAR
//   lgkm0 (drains own reads(u)); setprio(1); 16 MFMA; setprio(0)
// Race ledger (one-barrier, 5-ring):
//  - restage: slot read at phase u is next written by stage issued at phase
//    u+2 ((u+2)+3 === u mod 5). A wave issues that stage only after passing
//    BAR(u+1); every wave reaching BAR(u+1) has executed lgkm0+MFMA(u),
//    i.e. its reads(u) completed -> no overwrite race. (4-ring would restage
//    at u+1 with only BAR(u) between -> racy; hence 5 slots.)
//  - slot validity: vmcnt(4) at phase u leaves only stages of khalves
//    u+2,u+3 in flight (outstanding 6 -> 4), so khalf u+1's DMA landed;
//    BAR(u) publishes before any wave reads slot u+1 at phase u+1.
//    Inductive base: prologue stages khalves 0,1,2 then vmcnt(4); BAR.
//  - tail: first no-stage phase vmcnt(2), next vmcnt(0), last none.
// No sched_barrier anywhere: compiler is free to pipeline reads/stage into
// the window; barriers (asm volatile + memory) are the only fences.
// LDS swizzle unchanged (verified 2x: conflicts=0).
// Requires NH = K/32 >= 4 (call sites: NH = 32 or 8).
// ===========================================================================
#define G6_VM(n)   asm volatile("s_waitcnt vmcnt(" #n ")" ::: "memory")
#define G6_BAR()   asm volatile("s_barrier" ::: "memory")
#define G6_LGKM0() asm volatile("s_waitcnt lgkmcnt(0)" ::: "memory")

#define G6_KLOOP()                                                             \
  async_copy16(Ag,      &As[0 * 8192 + tid * 8]);                              \
  async_copy16(Bg,      &Bs[0 * 8192 + tid * 8]);                              \
  async_copy16(Ag + 32, &As[1 * 8192 + tid * 8]);                              \
  async_copy16(Bg + 32, &Bs[1 * 8192 + tid * 8]);                              \
  async_copy16(Ag + 64, &As[2 * 8192 + tid * 8]);                              \
  async_copy16(Bg + 64, &Bs[2 * 8192 + tid * 8]);                              \
  G6_VM(4); G6_BAR();                                                          \
  {                                                                            \
    int rs = 0, ws = 3, koff = 96;                                             \
    for (int u = 0; u < NH; ++u) {                                             \
      const __hip_bfloat16* Asl = As + rs * 8192;                              \
      const __hip_bfloat16* Bsl = Bs + rs * 8192;                              \
      shortx8 fa[4], fb[4];                                                    \
      _Pragma("unroll")                                                        \
      for (int i_ = 0; i_ < 4; ++i_)                                           \
        fa[i_] = *(const shortx8*)&Asl[ard + i_ * 512];                        \
      _Pragma("unroll")                                                        \
      for (int i_ = 0; i_ < 4; ++i_)                                           \
        fb[i_] = *(const shortx8*)&Bsl[brd + i_ * 512];                        \
      if (u + 3 < NH) {                                                        \
        async_copy16(Ag + koff, &As[ws * 8192 + tid * 8]);                     \
        async_copy16(Bg + koff, &Bs[ws * 8192 + tid * 8]);                     \
        koff += 32;                                                            \
        G6_VM(4);                                                              \
      } else if (u + 2 < NH) { G6_VM(2); }                                     \
      else if (u + 1 < NH)   { G6_VM(0); }                                     \
      G6_BAR();                                                                \
      G6_LGKM0();                                                              \
      __builtin_amdgcn_s_setprio(1);                                           \
      _Pragma("unroll")                                                        \
      for (int mi_ = 0; mi_ < 4; ++mi_)                                        \
        _Pragma("unroll")                                                      \
        for (int ni_ = 0; ni_ < 4; ++ni_)                                      \
          acc[mi_][ni_] = __builtin_amdgcn_mfma_f32_16x16x32_bf16(             \
              fa[mi_], fb[ni_], acc[mi_][ni_], 0, 0, 0);                       \
      __builtin_amdgcn_s_setprio(0);                                           \
      rs = (rs == 4) ? 0 : rs + 1;                                             \
      ws = (ws == 4) ? 0 : ws + 1;                                             \
    }                                                                          \
  }

// C[M,N] = A[M,K] * B[N,K]^T, bf16 in, fp32 acc, 256x256 tile, 1024 threads.
// EPI: 0 = +bias -> bf16; 1 = +bias, gelu -> bf16
template<int EPI>
__global__ __launch_bounds__(1024, 4) void gemm256(
    const __hip_bfloat16* __restrict__ A,   // [M,K]
    const __hip_bfloat16* __restrict__ B,   // [N,K]
    const float* __restrict__ bias,         // [N]
    __hip_bfloat16* __restrict__ outb,
    int M, int N, int K, int NT)
{
  __shared__ __align__(16) __hip_bfloat16 As[5 * 8192];
  __shared__ __align__(16) __hip_bfloat16 Bs[5 * 8192];
  const int tid  = threadIdx.x;
  const int lane = tid & 63;
  const int wave = tid >> 6;        // 0..15
  const int wr = wave >> 2;         // 0..3 (64-row band)
  const int wc = wave & 3;          // 0..3 (64-col band)
  const int fr = lane & 15;
  const int fq = lane >> 4;         // 0..3

  // bijective XCD swizzle (nwg % 8 == 0 for all call sites)
  const int nwg = gridDim.x;
  const int cpx = nwg >> 3;
  const int swz = (blockIdx.x & 7) * cpx + (blockIdx.x >> 3);
  const int mt = swz / NT, nt = swz % NT;
  const long bm = (long)mt * 256, bn = (long)nt * 256;

  // staging: thread t covers phys 16B-chunk (t&3) of row (t>>2) of a slot
  const int srow = tid >> 2;                       // 0..255
  const int sch  = (tid & 3) ^ ((tid >> 3) & 3);   // source k-chunk (involution)
  const __hip_bfloat16* Ag = A + (bm + srow) * (size_t)K + sch * 8;
  const __hip_bfloat16* Bg = B + (bn + srow) * (size_t)K + sch * 8;

  // ds_read bases (elements), swizzled chunk = fq ^ ((fr>>1)&3)
  const int swc = (fq ^ ((fr >> 1) & 3)) << 3;
  const int ard = (wr * 64 + fr) * 32 + swc;
  const int brd = (wc * 64 + fr) * 32 + swc;

  const floatx4 zero = {0.f, 0.f, 0.f, 0.f};
  floatx4 acc[4][4];
#pragma unroll
  for (int mi = 0; mi < 4; ++mi)
#pragma unroll
    for (int ni = 0; ni < 4; ++ni) acc[mi][ni] = zero;

  const int NH = K >> 5;            // k-halves of 32 (>= 4)
  G6_KLOOP()

  // epilogue: C/D layout col = lane&15, row = (lane>>4)*4 + reg
#pragma unroll
  for (int mi = 0; mi < 4; ++mi) {
#pragma unroll
    for (int ni = 0; ni < 4; ++ni) {
      const long col = bn + wc * 64 + ni * 16 + fr;
      const float bv = bias[col];
#pragma unroll
      for (int r = 0; r < 4; ++r) {
        const long row = bm + wr * 64 + mi * 16 + fq * 4 + r;
        float v = acc[mi][ni][r] + bv;
        if (EPI == 1) {
          const float u = v + 0.044715f * v * v * v;
          v = v / (1.0f + __expf(-1.5957691216057308f * u));
        }
        outb[(size_t)row * N + col] = __float2bfloat16(v);
      }
    }
  }
}

// ---------------------------------------------------------------------------
// 256x256 split-K GEMM (same engine) -> bf16 partials [SPLITS, M, N].
// attn-out: Klen=256 (NH=8); FFN2: Klen=1024 (NH=32).
// ---------------------------------------------------------------------------
__global__ __launch_bounds__(1024, 4) void gemm256_splitk(
    const __hip_bfloat16* __restrict__ A,   // [M,K]
    const __hip_bfloat16* __restrict__ B,   // [N,K]
    __hip_bfloat16* __restrict__ part,      // [SPLITS, M, N]
    int M, int N, int K, int Klen, int NT, int TPS)
{
  __shared__ __align__(16) __hip_bfloat16 As[5 * 8192];
  __shared__ __align__(16) __hip_bfloat16 Bs[5 * 8192];
  const int tid  = threadIdx.x;
  const int lane = tid & 63;
  const int wave = tid >> 6;
  const int wr = wave >> 2;
  const int wc = wave & 3;
  const int fr = lane & 15;
  const int fq = lane >> 4;

  const int nwg = gridDim.x;
  const int cpx = nwg >> 3;
  const int swz = (blockIdx.x & 7) * cpx + (blockIdx.x >> 3);
  const int zt = swz / TPS;
  const int tile = swz % TPS;
  const int mt = tile / NT, nt = tile % NT;
  const long bm = (long)mt * 256, bn = (long)nt * 256;
  const int kstart = zt * Klen;

  const int srow = tid >> 2;
  const int sch  = (tid & 3) ^ ((tid >> 3) & 3);
  const __hip_bfloat16* Ag = A + (bm + srow) * (size_t)K + kstart + sch * 8;
  const __hip_bfloat16* Bg = B + (bn + srow) * (size_t)K + kstart + sch * 8;

  const int swc = (fq ^ ((fr >> 1) & 3)) << 3;
  const int ard = (wr * 64 + fr) * 32 + swc;
  const int brd = (wc * 64 + fr) * 32 + swc;

  const floatx4 zero = {0.f, 0.f, 0.f, 0.f};
  floatx4 acc[4][4];
#pragma unroll
  for (int mi = 0; mi < 4; ++mi)
#pragma unroll
    for (int ni = 0; ni < 4; ++ni) acc[mi][ni] = zero;

  const int NH = Klen >> 5;
  G6_KLOOP()

  __hip_bfloat16* outp = part + (size_t)zt * M * N;
#pragma unroll
  for (int mi = 0; mi < 4; ++mi) {
#pragma unroll
    for (int ni = 0; ni < 4; ++ni) {
      const long col = bn + wc * 64 + ni * 16 + fr;
#pragma unroll
      for (int r = 0; r < 4; ++r) {
        const long row = bm + wr * 64 + mi * 16 + fq * 4 + r;
        outp[(size_t)row * N + col] = __float2bfloat16(acc[mi][ni][r]);
      }
    }
  }
}

// ---------------------------------------------------------------------------
// V transpose: qkv v-part [token, h*64+d] -> vt[(bh*64+d)*1024 + token]
// ---------------------------------------------------------------------------
__global__ __launch_bounds__(256) void transpose_v_kernel(
    const __hip_bfloat16* __restrict__ qkv, __hip_bfloat16* __restrict__ vt)
{
  const int bh = blockIdx.y;
  const int tt = blockIdx.x;
  const int b = bh >> 4, h = bh & 15;
  __shared__ __hip_bfloat16 tile[64][65];
  const int tid = threadIdx.x;
  const int r = tid >> 2;
  const int c = (tid & 3) << 4;
  const __hip_bfloat16* src = qkv + (size_t)(b * 1024 + tt * 64 + r) * 3072 + 2048 + h * 64 + c;
  U8 u0, u1;
  u0.v = *(const shortx8*)src;
  u1.v = *(const shortx8*)(src + 8);
#pragma unroll
  for (int j = 0; j < 8; ++j) { tile[r][c + j] = u0.h[j]; tile[r][c + 8 + j] = u1.h[j]; }
  __syncthreads();
  U8 w0, w1;
#pragma unroll
  for (int j = 0; j < 8; ++j) { w0.h[j] = tile[c + j][r]; w1.h[j] = tile[c + 8 + j][r]; }
  __hip_bfloat16* dst = vt + ((size_t)bh * 64 + r) * 1024 + tt * 64 + c;
  *(shortx8*)dst       = w0.v;
  *(shortx8*)(dst + 8) = w1.v;
}

// ---------------------------------------------------------------------------
// Banded-causal flash attention. One wave per (b,h,q-tile of 16).
// ---------------------------------------------------------------------------
__global__ __launch_bounds__(256) void attn_kernel(
    const __hip_bfloat16* __restrict__ qkv,
    const __hip_bfloat16* __restrict__ vt,
    __hip_bfloat16* __restrict__ ctx)
{
  const int wave = threadIdx.x >> 6;
  const int lane = threadIdx.x & 63;
  const int gw = blockIdx.x * 4 + wave;
  const int qt = gw & 63;
  const int bh = gw >> 6;
  const int b = bh >> 4, h = bh & 15;
  const int fr = lane & 15, fq = lane >> 4;
  const int q0 = qt << 4;

  __shared__ __align__(16) __hip_bfloat16 Plds[4][16 * 32];
  __hip_bfloat16* Pw = Plds[wave];

  const __hip_bfloat16* qrow = qkv + (size_t)(b * 1024 + q0 + fr) * 3072 + h * 64;
  const shortx8 aq0 = *(const shortx8*)(qrow + fq * 8);
  const shortx8 aq1 = *(const shortx8*)(qrow + 32 + fq * 8);

  const float SC = 0.125f * 1.44269504088896f;
  float m_r[4] = {-1e30f, -1e30f, -1e30f, -1e30f};
  float l_r[4] = {0.f, 0.f, 0.f, 0.f};
  const floatx4 zero = {0.f, 0.f, 0.f, 0.f};
  floatx4 o[4];
#pragma unroll
  for (int nd = 0; nd < 4; ++nd) o[nd] = zero;

  const int kt0 = (q0 >= 255) ? ((q0 - 255) >> 5) : 0;
  const int kt1 = (q0 + 15) >> 5;
  for (int kt = kt0; kt <= kt1; ++kt) {
    const int kbase = kt << 5;
    const __hip_bfloat16* krow0 = qkv + (size_t)(b * 1024 + kbase + fr) * 3072 + 1024 + h * 64;
    const __hip_bfloat16* krow1 = krow0 + 16 * 3072;
    const shortx8 bk00 = *(const shortx8*)(krow0 + fq * 8);
    const shortx8 bk01 = *(const shortx8*)(krow0 + 32 + fq * 8);
    const shortx8 bk10 = *(const shortx8*)(krow1 + fq * 8);
    const shortx8 bk11 = *(const shortx8*)(krow1 + 32 + fq * 8);
    floatx4 s0 = zero, s1 = zero;
    s0 = __builtin_amdgcn_mfma_f32_16x16x32_bf16(aq0, bk00, s0, 0, 0, 0);
    s0 = __builtin_amdgcn_mfma_f32_16x16x32_bf16(aq1, bk01, s0, 0, 0, 0);
    s1 = __builtin_amdgcn_mfma_f32_16x16x32_bf16(aq0, bk10, s1, 0, 0, 0);
    s1 = __builtin_amdgcn_mfma_f32_16x16x32_bf16(aq1, bk11, s1, 0, 0, 0);
#pragma unroll
    for (int r = 0; r < 4; ++r) { s0[r] *= SC; s1[r] *= SC; }
    if (kbase + 31 > q0 || kbase < q0 - 240) {
#pragma unroll
      for (int r = 0; r < 4; ++r) {
        const int tq = q0 + fq * 4 + r;
        const int j0 = kbase + fr;
        const int j1 = j0 + 16;
        if (j0 > tq || j0 < tq - 255) s0[r] = -3e38f;
        if (j1 > tq || j1 < tq - 255) s1[r] = -3e38f;
      }
    }
#pragma unroll
    for (int r = 0; r < 4; ++r) {
      float vmax = fmaxf(s0[r], s1[r]);
      vmax = fmaxf(vmax, __shfl_xor(vmax, 1));
      vmax = fmaxf(vmax, __shfl_xor(vmax, 2));
      vmax = fmaxf(vmax, __shfl_xor(vmax, 4));
      vmax = fmaxf(vmax, __shfl_xor(vmax, 8));
      const float mnew = fmaxf(m_r[r], vmax);
      const float alpha = exp2f(m_r[r] - mnew);
      const float p0 = exp2f(s0[r] - mnew);
      const float p1 = exp2f(s1[r] - mnew);
      m_r[r] = mnew;
      float ps = p0 + p1;
      ps += __shfl_xor(ps, 1);
      ps += __shfl_xor(ps, 2);
      ps += __shfl_xor(ps, 4);
      ps += __shfl_xor(ps, 8);
      l_r[r] = l_r[r] * alpha + ps;
      o[0][r] *= alpha; o[1][r] *= alpha; o[2][r] *= alpha; o[3][r] *= alpha;
      Pw[(fq * 4 + r) * 32 + fr]      = __float2bfloat16(p0);
      Pw[(fq * 4 + r) * 32 + 16 + fr] = __float2bfloat16(p1);
    }
    asm volatile("s_waitcnt lgkmcnt(0)" ::: "memory");
    const shortx8 ap = *(const shortx8*)&Pw[fr * 32 + fq * 8];
#pragma unroll
    for (int nd = 0; nd < 4; ++nd) {
      const shortx8 bv = *(const shortx8*)&vt[((size_t)bh * 64 + nd * 16 + fr) * 1024 + kbase + fq * 8];
      o[nd] = __builtin_amdgcn_mfma_f32_16x16x32_bf16(ap, bv, o[nd], 0, 0, 0);
    }
    asm volatile("s_waitcnt lgkmcnt(0)" ::: "memory");
  }
#pragma unroll
  for (int nd = 0; nd < 4; ++nd)
#pragma unroll
    for (int r = 0; r < 4; ++r)
      ctx[(size_t)(b * 1024 + q0 + fq * 4 + r) * 1024 + h * 64 + nd * 16 + fr] =
          __float2bfloat16(o[nd][r] / l_r[r]);
}

// ---------------------------------------------------------------------------
// Fused split-K reduce (bf16 partials) + bias + residual + LayerNorm.
// ---------------------------------------------------------------------------
template<int S, int WB>
__global__ __launch_bounds__(256) void ln_sum_kernel(
    const __hip_bfloat16* __restrict__ part,  // [S, 4096, 1024] bf16
    const float* __restrict__ resid,          // [4096, 1024]
    const float* __restrict__ bias,           // [1024]
    const float* __restrict__ g, const float* __restrict__ be,
    float* __restrict__ outf, __hip_bfloat16* __restrict__ outb)
{
  const int row = blockIdx.x;
  const int tid = threadIdx.x;
  const size_t base = (size_t)row * 1024;
  float4 v = ((const float4*)(resid + base))[tid];
  const float4 bv = ((const float4*)bias)[tid];
  v.x += bv.x; v.y += bv.y; v.z += bv.z; v.w += bv.w;
#pragma unroll
  for (int s = 0; s < S; ++s) {
    U4 p;
    p.v = *(const unsigned long long*)&part[(size_t)s * 4096 * 1024 + base + tid * 4];
    v.x += __bfloat162float(p.h[0]);
    v.y += __bfloat162float(p.h[1]);
    v.z += __bfloat162float(p.h[2]);
    v.w += __bfloat162float(p.h[3]);
  }
  float sm = v.x + v.y + v.z + v.w;
  float ss = v.x * v.x + v.y * v.y + v.z * v.z + v.w * v.w;
#pragma unroll
  for (int off = 1; off < 64; off <<= 1) {
    sm += __shfl_xor(sm, off);
    ss += __shfl_xor(ss, off);
  }
  __shared__ float red[8];
  if ((tid & 63) == 0) { red[tid >> 6] = sm; red[4 + (tid >> 6)] = ss; }
  __syncthreads();
  sm = red[0] + red[1] + red[2] + red[3];
  ss = red[4] + red[5] + red[6] + red[7];
  const float mu = sm * (1.0f / 1024.0f);
  const float rs = rsqrtf(ss * (1.0f / 1024.0f) - mu * mu + 1e-5f);
  const float4 gg = ((const float4*)g)[tid];
  const float4 bb = ((const float4*)be)[tid];
  float4 y;
  y.x = (v.x - mu) * rs * gg.x + bb.x;
  y.y = (v.y - mu) * rs * gg.y + bb.y;
  y.z = (v.z - mu) * rs * gg.z + bb.z;
  y.w = (v.w - mu) * rs * gg.w + bb.w;
  ((float4*)(outf + base))[tid] = y;
  if (WB) {
    bf4 o4;
    o4.h[0] = __float2bfloat16(y.x);
    o4.h[1] = __float2bfloat16(y.y);
    o4.h[2] = __float2bfloat16(y.z);
    o4.h[3] = __float2bfloat16(y.w);
    *(bf4*)(outb + base + tid * 4) = o4;
  }
}

// ---------------------------------------------------------------------------
extern "C" void kernel_launch(void* const* d_in, const int* in_sizes, int n_in,
                              void* d_out, int out_size, void* d_ws, size_t ws_size,
                              hipStream_t stream) {
  const float* x    = (const float*)d_in[0];
  const float* Wqkv = (const float*)d_in[1];
  const float* bqkv = (const float*)d_in[2];
  const float* Wo   = (const float*)d_in[3];
  const float* bo   = (const float*)d_in[4];
  const float* W1   = (const float*)d_in[5];
  const float* b1   = (const float*)d_in[6];
  const float* W2   = (const float*)d_in[7];
  const float* b2   = (const float*)d_in[8];
  const float* g1   = (const float*)d_in[9];
  const float* be1  = (const float*)d_in[10];
  const float* g2   = (const float*)d_in[11];
  const float* be2  = (const float*)d_in[12];

  char* ws = (char*)d_ws;
  size_t off = 0;
  auto alloc = [&](size_t bytes) -> void* {
    void* p = ws + off;
    off += (bytes + 255) & ~(size_t)255;
    return p;
  };
  __hip_bfloat16* wqkvb = (__hip_bfloat16*)alloc(6291456);
  __hip_bfloat16* wob   = (__hip_bfloat16*)alloc(2097152);
  __hip_bfloat16* w1b   = (__hip_bfloat16*)alloc(8388608);
  __hip_bfloat16* w2b   = (__hip_bfloat16*)alloc(8388608);
  __hip_bfloat16* xb    = (__hip_bfloat16*)alloc(8388608);
  __hip_bfloat16* qkvb  = (__hip_bfloat16*)alloc(25165824);
  __hip_bfloat16* vtb   = (__hip_bfloat16*)alloc(8388608);
  __hip_bfloat16* ctxb  = (__hip_bfloat16*)alloc(8388608);
  __hip_bfloat16* part  = (__hip_bfloat16*)alloc(4u * 8388608);
  float*          x1f   = (float*)alloc(16777216);
  __hip_bfloat16* x1b   = (__hip_bfloat16*)alloc(8388608);
  __hip_bfloat16* hb    = (__hip_bfloat16*)alloc(33554432);
  (void)ws_size; (void)in_sizes; (void)n_in; (void)out_size;

  // 0. single-launch cast of x + all weights to bf16
  cast_all_kernel<<<16384, 256, 0, stream>>>(x, xb, 4096,
                                             Wqkv, wqkvb, 3072,
                                             Wo, wob, 1024,
                                             W1, w1b, 4096,
                                             W2, w2b);
  // 1. QKV projection (256x256, 16-wave, 192 wgs)
  gemm256<0><<<192, 1024, 0, stream>>>(xb, wqkvb, bqkv, qkvb, 4096, 3072, 1024, 12);
  // 2. attention
  transpose_v_kernel<<<dim3(16, 64), 256, 0, stream>>>(qkvb, vtb);
  attn_kernel<<<1024, 256, 0, stream>>>(qkvb, vtb, ctxb);
  // 3. output projection: split-K=4 (64 tiles x 4 = 256 wgs, NH=8)
  gemm256_splitk<<<256, 1024, 0, stream>>>(ctxb, wob, part, 4096, 1024, 1024, 256, 4, 64);
  ln_sum_kernel<4, 1><<<4096, 256, 0, stream>>>(part, x, bo, g1, be1, x1f, x1b);
  // 4. FFN (FFN1: 256 wgs = 1/CU)
  gemm256<1><<<256, 1024, 0, stream>>>(x1b, w1b, b1, hb, 4096, 4096, 1024, 16);
  // FFN2: split-K=4 (64 tiles x 4 splits = 256 wgs, NH=32)
  gemm256_splitk<<<256, 1024, 0, stream>>>(hb, w2b, part, 4096, 1024, 4096, 1024, 4, 64);
  ln_sum_kernel<4, 0><<<4096, 256, 0, stream>>>(part, x1f, b2, g2, be2, (float*)d_out, nullptr);
}